// Round 1
// baseline (1035.804 us; speedup 1.0000x reference)
//
#include <hip/hip_runtime.h>

#define N_NODES   40000
#define N_EDGES   640000
#define N_GRAPHS  64
#define DIM_IN    32
#define N_ETYPE   16
#define DH        128
#define DOUT      256
#define T_ITERS   4

// ---------------- node embedding: h = x @ Wn + bn ----------------
__global__ __launch_bounds__(256) void k_embed(const float* __restrict__ x,
                                               const float* __restrict__ Wn,
                                               const float* __restrict__ bn,
                                               float* __restrict__ h) {
  int idx = blockIdx.x * 256 + threadIdx.x;     // n*128 + c, exact grid
  int n = idx >> 7, c = idx & 127;
  const float* xr = x + n * DIM_IN;
  float acc = bn[c];
#pragma unroll
  for (int k = 0; k < DIM_IN; ++k)
    acc = fmaf(xr[k], Wn[k * DH + c], acc);
  h[idx] = acc;
}

// ---------------- CSR build ----------------
__global__ __launch_bounds__(256) void k_hist(const int* __restrict__ dst,
                                              int* __restrict__ counts) {
  int i = blockIdx.x * 256 + threadIdx.x;
  atomicAdd(&counts[dst[i]], 1);
}

__global__ __launch_bounds__(1024) void k_scan(const int* __restrict__ counts,
                                               int* __restrict__ row_start,
                                               int* __restrict__ cursor) {
  __shared__ int wsums[16];
  __shared__ int s_carry;
  int tid = threadIdx.x, lane = tid & 63, w = tid >> 6;
  if (tid == 0) s_carry = 0;
  __syncthreads();
  for (int base = 0; base < N_NODES; base += 1024) {
    int i = base + tid;
    int v = (i < N_NODES) ? counts[i] : 0;
    int s = v;
#pragma unroll
    for (int off = 1; off < 64; off <<= 1) {
      int t = __shfl_up(s, off);
      if (lane >= off) s += t;
    }
    if (lane == 63) wsums[w] = s;
    __syncthreads();
    if (tid < 16) {
      int ws_ = wsums[tid];
#pragma unroll
      for (int off = 1; off < 16; off <<= 1) {
        int t = __shfl_up(ws_, off);
        if (tid >= off) ws_ += t;
      }
      wsums[tid] = ws_;
    }
    __syncthreads();
    int excl = s_carry + s - v + (w ? wsums[w - 1] : 0);
    if (i < N_NODES) { row_start[i] = excl; cursor[i] = excl; }
    __syncthreads();
    if (tid == 0) s_carry += wsums[15];
    __syncthreads();
  }
  if (threadIdx.x == 0) row_start[N_NODES] = s_carry;
}

__global__ __launch_bounds__(256) void k_permute(const int* __restrict__ src,
                                                 const int* __restrict__ dst,
                                                 int* __restrict__ cursor,
                                                 int* __restrict__ src_perm,
                                                 int* __restrict__ eid_perm) {
  int i = blockIdx.x * 256 + threadIdx.x;
  int d = dst[i];
  int pos = atomicAdd(&cursor[d], 1);
  src_perm[pos] = src[i];
  eid_perm[pos] = i;
}

// -------- aggregation: z[n] = h[n] + sum_in_edges relu(h[src] + ea@We + be) --------
// one wave per node; lane owns cols {lane, lane+64}; We columns in registers.
__global__ __launch_bounds__(256) void k_agg(const float* __restrict__ h,
                                             const float* __restrict__ edge_attr,
                                             const float* __restrict__ We,
                                             const float* __restrict__ be,
                                             const int* __restrict__ row_start,
                                             const int* __restrict__ src_perm,
                                             const int* __restrict__ eid_perm,
                                             float* __restrict__ z) {
  int lane = threadIdx.x & 63;
  int n = (blockIdx.x << 2) + (threadIdx.x >> 6);
  float we0[N_ETYPE], we1[N_ETYPE];
#pragma unroll
  for (int k = 0; k < N_ETYPE; ++k) {
    we0[k] = We[k * DH + lane];
    we1[k] = We[k * DH + 64 + lane];
  }
  float be0 = be[lane], be1 = be[64 + lane];
  float acc0 = h[n * DH + lane];
  float acc1 = h[n * DH + 64 + lane];
  int beg = row_start[n], end = row_start[n + 1];
  for (int i = beg; i < end; ++i) {
    int s = src_perm[i];
    int eid = eid_perm[i];
    const float4* ea = (const float4*)(edge_attr + (size_t)eid * N_ETYPE);
    float4 a0 = ea[0], a1 = ea[1], a2 = ea[2], a3 = ea[3];
    float hs0 = h[s * DH + lane];
    float hs1 = h[s * DH + 64 + lane];
    float e0 = be0, e1 = be1;
    e0 = fmaf(a0.x, we0[0], e0);  e1 = fmaf(a0.x, we1[0], e1);
    e0 = fmaf(a0.y, we0[1], e0);  e1 = fmaf(a0.y, we1[1], e1);
    e0 = fmaf(a0.z, we0[2], e0);  e1 = fmaf(a0.z, we1[2], e1);
    e0 = fmaf(a0.w, we0[3], e0);  e1 = fmaf(a0.w, we1[3], e1);
    e0 = fmaf(a1.x, we0[4], e0);  e1 = fmaf(a1.x, we1[4], e1);
    e0 = fmaf(a1.y, we0[5], e0);  e1 = fmaf(a1.y, we1[5], e1);
    e0 = fmaf(a1.z, we0[6], e0);  e1 = fmaf(a1.z, we1[6], e1);
    e0 = fmaf(a1.w, we0[7], e0);  e1 = fmaf(a1.w, we1[7], e1);
    e0 = fmaf(a2.x, we0[8], e0);  e1 = fmaf(a2.x, we1[8], e1);
    e0 = fmaf(a2.y, we0[9], e0);  e1 = fmaf(a2.y, we1[9], e1);
    e0 = fmaf(a2.z, we0[10], e0); e1 = fmaf(a2.z, we1[10], e1);
    e0 = fmaf(a2.w, we0[11], e0); e1 = fmaf(a2.w, we1[11], e1);
    e0 = fmaf(a3.x, we0[12], e0); e1 = fmaf(a3.x, we1[12], e1);
    e0 = fmaf(a3.y, we0[13], e0); e1 = fmaf(a3.y, we1[13], e1);
    e0 = fmaf(a3.z, we0[14], e0); e1 = fmaf(a3.z, we1[14], e1);
    e0 = fmaf(a3.w, we0[15], e0); e1 = fmaf(a3.w, we1[15], e1);
    acc0 += fmaxf(hs0 + e0, 0.0f);
    acc1 += fmaxf(hs1 + e1, 0.0f);
  }
  z[n * DH + lane] = acc0;
  z[n * DH + 64 + lane] = acc1;
}

// ---------------- MLP: h = relu(z@W1+b1)@W2+b2, fused pooling ----------------
__device__ __forceinline__ void gemm_tile(const float* sA, const float* sW,
                                          float acc[8][4], int r0, int c0) {
#pragma unroll 4
  for (int k = 0; k < DH; k += 2) {
    float4 w0 = *(const float4*)&sW[k * DH + c0];
    float4 w1 = *(const float4*)&sW[(k + 1) * DH + c0];
#pragma unroll
    for (int i = 0; i < 8; ++i) {
      float2 a = *(const float2*)&sA[(r0 + i) * 132 + k];
      acc[i][0] = fmaf(a.x, w0.x, acc[i][0]);
      acc[i][1] = fmaf(a.x, w0.y, acc[i][1]);
      acc[i][2] = fmaf(a.x, w0.z, acc[i][2]);
      acc[i][3] = fmaf(a.x, w0.w, acc[i][3]);
      acc[i][0] = fmaf(a.y, w1.x, acc[i][0]);
      acc[i][1] = fmaf(a.y, w1.y, acc[i][1]);
      acc[i][2] = fmaf(a.y, w1.z, acc[i][2]);
      acc[i][3] = fmaf(a.y, w1.w, acc[i][3]);
    }
  }
}

__global__ __launch_bounds__(256) void k_mlp(const float* __restrict__ z,
                                             const float* __restrict__ W1,
                                             const float* __restrict__ b1,
                                             const float* __restrict__ W2,
                                             const float* __restrict__ b2,
                                             const int* __restrict__ graph_ids,
                                             float* __restrict__ h_out,
                                             float* __restrict__ pooled,
                                             int t_slot) {
  __shared__ float sA[64 * 132];
  __shared__ float sW[DH * DH];
  int tid = threadIdx.x;
  int rb = blockIdx.x * 64;
  for (int idx = tid; idx < 64 * DH; idx += 256) {
    int r = idx >> 7, k = idx & 127;
    sA[r * 132 + k] = z[(rb + r) * DH + k];
  }
  for (int idx = tid; idx < DH * DH; idx += 256) sW[idx] = W1[idx];
  __syncthreads();

  int cg = tid & 31, rg = tid >> 5;
  int c0 = cg << 2, r0 = rg << 3;
  float acc[8][4];
  {
    float4 bb = *(const float4*)&b1[c0];
#pragma unroll
    for (int i = 0; i < 8; ++i) { acc[i][0] = bb.x; acc[i][1] = bb.y; acc[i][2] = bb.z; acc[i][3] = bb.w; }
  }
  gemm_tile(sA, sW, acc, r0, c0);
  __syncthreads();
  // t = relu(acc) -> sA ; stage W2
#pragma unroll
  for (int i = 0; i < 8; ++i) {
    float4 v;
    v.x = fmaxf(acc[i][0], 0.0f); v.y = fmaxf(acc[i][1], 0.0f);
    v.z = fmaxf(acc[i][2], 0.0f); v.w = fmaxf(acc[i][3], 0.0f);
    *(float4*)&sA[(r0 + i) * 132 + c0] = v;
  }
  for (int idx = tid; idx < DH * DH; idx += 256) sW[idx] = W2[idx];
  __syncthreads();
  {
    float4 bb = *(const float4*)&b2[c0];
#pragma unroll
    for (int i = 0; i < 8; ++i) { acc[i][0] = bb.x; acc[i][1] = bb.y; acc[i][2] = bb.z; acc[i][3] = bb.w; }
  }
  gemm_tile(sA, sW, acc, r0, c0);

  // epilogue: write h, pool into pooled[g][t*128 + c]
  int node0 = rb + r0;
#pragma unroll
  for (int i = 0; i < 8; ++i) {
    float4 v = make_float4(acc[i][0], acc[i][1], acc[i][2], acc[i][3]);
    *(float4*)&h_out[(size_t)(node0 + i) * DH + c0] = v;
  }
  float* pbase = pooled + t_slot * DH;
  int g_first = graph_ids[node0];
  int g_last = graph_ids[node0 + 7];
  if (g_first == g_last) {
    float s0 = 0.f, s1 = 0.f, s2 = 0.f, s3 = 0.f;
#pragma unroll
    for (int i = 0; i < 8; ++i) { s0 += acc[i][0]; s1 += acc[i][1]; s2 += acc[i][2]; s3 += acc[i][3]; }
    atomicAdd(&pbase[g_first * 512 + c0 + 0], s0);
    atomicAdd(&pbase[g_first * 512 + c0 + 1], s1);
    atomicAdd(&pbase[g_first * 512 + c0 + 2], s2);
    atomicAdd(&pbase[g_first * 512 + c0 + 3], s3);
  } else {
#pragma unroll
    for (int i = 0; i < 8; ++i) {
      int g = graph_ids[node0 + i];
      atomicAdd(&pbase[g * 512 + c0 + 0], acc[i][0]);
      atomicAdd(&pbase[g * 512 + c0 + 1], acc[i][1]);
      atomicAdd(&pbase[g * 512 + c0 + 2], acc[i][2]);
      atomicAdd(&pbase[g * 512 + c0 + 3], acc[i][3]);
    }
  }
}

// ---------------- final: out = pooled @ Wl + bl ----------------
__global__ __launch_bounds__(256) void k_final(const float* __restrict__ pooled,
                                               const float* __restrict__ Wl,
                                               const float* __restrict__ bl,
                                               float* __restrict__ out) {
  int g = blockIdx.x, o = threadIdx.x;
  __shared__ float sp[DH * T_ITERS];
  for (int idx = o; idx < DH * T_ITERS; idx += 256) sp[idx] = pooled[g * (DH * T_ITERS) + idx];
  __syncthreads();
  float acc = bl[o];
#pragma unroll 8
  for (int j = 0; j < DH * T_ITERS; ++j)
    acc = fmaf(sp[j], Wl[j * DOUT + o], acc);
  out[g * DOUT + o] = acc;
}

extern "C" void kernel_launch(void* const* d_in, const int* in_sizes, int n_in,
                              void* d_out, int out_size, void* d_ws, size_t ws_size,
                              hipStream_t stream) {
  const float* x         = (const float*)d_in[0];
  const int*   edge_index= (const int*)d_in[1];
  const float* edge_attr = (const float*)d_in[2];
  const int*   graph_ids = (const int*)d_in[3];
  const float* Wn = (const float*)d_in[4];
  const float* bn = (const float*)d_in[5];
  const float* We = (const float*)d_in[6];
  const float* be = (const float*)d_in[7];
  const float* W1 = (const float*)d_in[8];
  const float* b1 = (const float*)d_in[9];
  const float* W2 = (const float*)d_in[10];
  const float* b2 = (const float*)d_in[11];
  const float* Wl = (const float*)d_in[12];
  const float* bl = (const float*)d_in[13];
  float* out = (float*)d_out;

  char* p = (char*)d_ws;
  auto alloc = [&](size_t bytes) { char* r = p; p += (bytes + 255) & ~(size_t)255; return r; };
  float* h        = (float*)alloc((size_t)N_NODES * DH * 4);
  float* z        = (float*)alloc((size_t)N_NODES * DH * 4);
  float* pooled   = (float*)alloc((size_t)N_GRAPHS * DH * T_ITERS * 4);
  int*   counts   = (int*)alloc((size_t)N_NODES * 4);
  int*   row_start= (int*)alloc((size_t)(N_NODES + 1) * 4);
  int*   cursor   = (int*)alloc((size_t)N_NODES * 4);
  int*   src_perm = (int*)alloc((size_t)N_EDGES * 4);
  int*   eid_perm = (int*)alloc((size_t)N_EDGES * 4);

  const int* src = edge_index;
  const int* dst = edge_index + N_EDGES;

  hipMemsetAsync(counts, 0, (size_t)N_NODES * 4, stream);
  hipMemsetAsync(pooled, 0, (size_t)N_GRAPHS * DH * T_ITERS * 4, stream);

  k_embed<<<N_NODES * DH / 256, 256, 0, stream>>>(x, Wn, bn, h);
  k_hist<<<N_EDGES / 256, 256, 0, stream>>>(dst, counts);
  k_scan<<<1, 1024, 0, stream>>>(counts, row_start, cursor);
  k_permute<<<N_EDGES / 256, 256, 0, stream>>>(src, dst, cursor, src_perm, eid_perm);

  for (int t = 0; t < T_ITERS; ++t) {
    k_agg<<<N_NODES / 4, 256, 0, stream>>>(h, edge_attr, We, be, row_start, src_perm, eid_perm, z);
    k_mlp<<<N_NODES / 64, 256, 0, stream>>>(z, W1, b1, W2, b2, graph_ids, h, pooled, t);
  }
  k_final<<<N_GRAPHS, 256, 0, stream>>>(pooled, Wl, bl, out);
}